// Round 6
// baseline (70.284 us; speedup 1.0000x reference)
//
#include <hip/hip_runtime.h>
#include <math.h>

typedef __attribute__((ext_vector_type(8))) short short8;
typedef __attribute__((ext_vector_type(4))) float f32x4;

namespace {
constexpr int NEL   = 4;
constexpr int NEXP  = 16;
constexpr int Bb    = 128;
constexpr int Aa    = 128;
constexpr int Cc    = 256;
constexpr int FATOM = 176;
constexpr int FPAIR = 32;
constexpr int FIN   = 384;
constexpr int HH1   = 128;
constexpr int HH2   = 96;
constexpr int NP    = Bb * Cc;               // 32768
constexpr int BUCKET_CAP = 4096;

// ws int offsets
constexpr int WS_COUNTS = 0;                 // 16 ints
constexpr int WS_BUCKET = 64;                // 16 * 4096 ints
constexpr int WS_BF     = 65600;             // shorts from here
constexpr int SYM_N   = Bb * Aa * FATOM;     // 2,883,584
constexpr int PAIR_N  = Bb * Cc * FPAIR;     // 1,048,576
constexpr int W1T_N   = NEXP * HH1 * FIN;    // 786,432  (packed [e][12][128][32])
constexpr int W2T_N   = NEXP * HH2 * HH1;    // 196,608  (packed [e][4][96][32])

// fused prep grid layout
constexpr int CVT_BLOCKS = (SYM_N / 4 + PAIR_N / 4) / 256;  // 3840
constexpr int W1_BLOCKS  = 768;
constexpr int W2_BLOCKS  = 192;
constexpr int IDX_BLOCKS = NP / 256;                        // 128
constexpr int W1_BASE  = CVT_BLOCKS;
constexpr int W2_BASE  = W1_BASE + W1_BLOCKS;
constexpr int IDX_BASE = W2_BASE + W2_BLOCKS;
constexpr int PREP_GRID = IDX_BASE + IDX_BLOCKS;            // 4928
}

__device__ inline float bf2f(short s) {
    unsigned u = ((unsigned)(unsigned short)s) << 16;
    return __builtin_bit_cast(float, u);
}
__device__ inline short f2bf(float f) {
    unsigned u = __builtin_bit_cast(unsigned, f);
    unsigned r = (u + 0x7FFFu + ((u >> 16) & 1u)) >> 16;
    return (short)r;
}
__device__ inline float celu1(float v) {
    return v > 0.f ? v : (__expf(v) - 1.0f);
}

// ---- fused prep: cvt_x | W1 pack | W2 pack | expert index (unchanged from R5) ----
__global__ __launch_bounds__(256) void k_prep(
    const float* __restrict__ sym, const float* __restrict__ pairf,
    short* __restrict__ symb, short* __restrict__ pairfb,
    const float* __restrict__ W1, const float* __restrict__ W2,
    short* __restrict__ w1tb, short* __restrict__ w2tb,
    const int* __restrict__ conn, const int* __restrict__ elements,
    int* __restrict__ counts, int* __restrict__ bucket,
    float* __restrict__ out)
{
    __shared__ float T[32][33];
    __shared__ int sh_cnt[NEXP], sh_base[NEXP];

    int bid = blockIdx.x;
    int t = threadIdx.x;

    if (bid < CVT_BLOCKS) {
        int i = bid * 256 + t;
        constexpr int NS4 = SYM_N / 4;
        const float4* src; short* dst; int j;
        if (i < NS4) { src = (const float4*)sym;   dst = symb;   j = i; }
        else         { src = (const float4*)pairf; dst = pairfb; j = i - NS4; }
        float4 v = src[j];
        short4 o;
        o.x = f2bf(v.x); o.y = f2bf(v.y); o.z = f2bf(v.z); o.w = f2bf(v.w);
        *(short4*)(dst + 4 * (size_t)j) = o;
    } else if (bid < IDX_BASE) {
        const float* src; short* dst; int K, N, k0, n0;
        if (bid < W2_BASE) {
            int b1i = bid - W1_BASE;
            int e = b1i / 48, tl = b1i % 48;
            K = FIN; N = HH1; k0 = (tl % 12) * 32; n0 = (tl / 12) * 32;
            src = W1 + (size_t)e * K * N;
            dst = w1tb + (size_t)e * 12 * HH1 * 32;
        } else {
            int b2i = bid - W2_BASE;
            int e = b2i / 12, tl = b2i % 12;
            K = HH1; N = HH2; k0 = (tl % 4) * 32; n0 = (tl / 4) * 32;
            src = W2 + (size_t)e * K * N;
            dst = w2tb + (size_t)e * 4 * HH2 * 32;
        }
        int tx = t & 31, ty = t >> 5;
        int ks = k0 >> 5;
#pragma unroll
        for (int j = 0; j < 4; ++j) {
            int r = ty + 8 * j;
            T[r][tx] = src[(size_t)(k0 + r) * N + n0 + tx];
        }
        __syncthreads();
#pragma unroll
        for (int j = 0; j < 4; ++j) {
            int n = n0 + ty + 8 * j;
            dst[(size_t)(ks * N + n) * 32 + tx] = f2bf(T[tx][ty + 8 * j]);
        }
    } else {
        int p = (bid - IDX_BASE) * 256 + t;
        if (t < NEXP) sh_cnt[t] = 0;
        __syncthreads();
        int e = -1, r = 0;
        {
            int c0 = conn[2 * p], c1 = conn[2 * p + 1];
            if (c0 != -1) {
                int b = p / Cc;
                int i0 = b * Aa + c0; if (i0 < 0) i0 += Bb * Aa;
                int i1 = b * Aa + c1; if (i1 < 0) i1 += Bb * Aa;
                e = elements[i0] * NEL + elements[i1];
            }
            if (e < 0 || e >= NEXP) {
                out[2 * p] = 0.f; out[2 * p + 1] = 0.f;
                e = -1;
            } else {
                r = atomicAdd(&sh_cnt[e], 1);
            }
        }
        __syncthreads();
        if (t < NEXP) sh_base[t] = (sh_cnt[t] > 0) ? atomicAdd(&counts[t], sh_cnt[t]) : 0;
        __syncthreads();
        if (e >= 0) {
            int pos = sh_base[e] + r;
            if (pos < BUCKET_CAP) bucket[e * BUCKET_CAP + pos] = p;
        }
    }
}

// ---- MFMA MoE: expert-persistent blocks, weights in registers ----
// grid = 256 blocks: e = bid & 15 (all shards of an expert on one XCD), shard = bid >> 4
// block = 256 thr = 4 waves, 1 wave/SIMD. Tile = 64 pairs.
// wave w: L1 cols [32w, 32w+32); L2/L3 pairs [16w, 16w+16).

#define LOADA(buf, mi) do {                                                   \
    const short* _fa = fa[mi]; const short* _fb = fb[mi]; const short* _pf = pf[mi]; \
    buf[0]  = *(const short8*)(_fa + 8 * lg);                                 \
    buf[1]  = *(const short8*)(_fa + 32 + 8 * lg);                            \
    buf[2]  = *(const short8*)(_fa + 64 + 8 * lg);                            \
    buf[3]  = *(const short8*)(_fa + 96 + 8 * lg);                            \
    buf[4]  = *(const short8*)(_fa + 128 + 8 * lg);                           \
    buf[5]  = *(const short8*)((lg < 2 ? _fa + 160 : _fb - 16) + 8 * lg);     \
    buf[6]  = *(const short8*)(_fb + 16 + 8 * lg);                            \
    buf[7]  = *(const short8*)(_fb + 48 + 8 * lg);                            \
    buf[8]  = *(const short8*)(_fb + 80 + 8 * lg);                            \
    buf[9]  = *(const short8*)(_fb + 112 + 8 * lg);                           \
    buf[10] = *(const short8*)(_fb + 144 + 8 * lg);                           \
    buf[11] = *(const short8*)(_pf + 8 * lg);                                 \
} while (0)

#define L1MFMA(mi, buf) do {                                                  \
    _Pragma("unroll")                                                         \
    for (int ks = 0; ks < 12; ++ks) {                                         \
        acc[mi][0] = __builtin_amdgcn_mfma_f32_16x16x32_bf16(buf[ks], w1r[ks][0], acc[mi][0], 0, 0, 0); \
        acc[mi][1] = __builtin_amdgcn_mfma_f32_16x16x32_bf16(buf[ks], w1r[ks][1], acc[mi][1], 0, 0, 0); \
    }                                                                         \
} while (0)

__global__ __launch_bounds__(256, 1) void k_moe(
    const int* __restrict__ counts, const int* __restrict__ bucket,
    const int* __restrict__ conn,
    const short* __restrict__ symb, const short* __restrict__ pairfb,
    const short* __restrict__ w1tb, const short* __restrict__ w2tb,
    const float* __restrict__ b1, const float* __restrict__ b2,
    const float* __restrict__ W3, const float* __restrict__ b3,
    float* __restrict__ out)
{
    __shared__ short H1s[2][64 * HH1];         // 2 x 16 KB, granule-XOR swizzled

    int e     = blockIdx.x & 15;
    int shard = blockIdx.x >> 4;
    int cnt = counts[e];
    if (cnt > BUCKET_CAP) cnt = BUCKET_CAP;
    int nt = (cnt + 63) >> 6;

    int t  = threadIdx.x;
    int w  = t >> 6;
    int lr = t & 15, lg = (t >> 4) & 3;

    // ---- prologue: expert weights into registers ----
    const short* w1p_e = w1tb + (size_t)e * 12 * HH1 * 32;
    const short* w2p_e = w2tb + (size_t)e * 4 * HH2 * 32;
    short8 w1r[12][2];
#pragma unroll
    for (int ks = 0; ks < 12; ++ks)
#pragma unroll
        for (int j = 0; j < 2; ++j)
            w1r[ks][j] = *(const short8*)(w1p_e + ((size_t)(ks * HH1 + (w * 32 + j * 16 + lr)) * 32) + 8 * lg);
    short8 w2r[6][4];
#pragma unroll
    for (int t6 = 0; t6 < 6; ++t6)
#pragma unroll
        for (int ks = 0; ks < 4; ++ks)
            w2r[t6][ks] = *(const short8*)(w2p_e + ((size_t)(ks * HH2 + (t6 * 16 + lr)) * 32) + 8 * lg);

    float b1v[2];
#pragma unroll
    for (int j = 0; j < 2; ++j) b1v[j] = b1[e * HH1 + w * 32 + j * 16 + lr];
    float b2v[6][4];
    float2 w3v[6][4];
#pragma unroll
    for (int t6 = 0; t6 < 6; ++t6)
#pragma unroll
        for (int r2 = 0; r2 < 4; ++r2) {
            int n2 = t6 * 16 + 4 * lg + r2;
            b2v[t6][r2] = b2[e * HH2 + n2];
            w3v[t6][r2] = ((const float2*)W3)[e * HH2 + n2];
        }
    float2 b3v = ((const float2*)b3)[e];

    const int* bucket_e = bucket + e * BUCKET_CAP;

    for (int tile = shard; tile < nt; tile += 16) {
        int tb = tile * 64;
        int buf = tile & 1;

        // ---- per-lane pair metadata (no LDS, no barrier) ----
        int pv[4];
#pragma unroll
        for (int mi = 0; mi < 4; ++mi) {
            int ii = tb + mi * 16 + lr;
            pv[mi] = bucket_e[ii < cnt ? ii : cnt - 1];
        }
        int2 cc[4];
#pragma unroll
        for (int mi = 0; mi < 4; ++mi) cc[mi] = ((const int2*)conn)[pv[mi]];
        const short *fa[4], *fb[4], *pf[4];
#pragma unroll
        for (int mi = 0; mi < 4; ++mi) {
            int bb = (pv[mi] >> 8) << 7;          // batch * Aa
            fa[mi] = symb + (size_t)(bb + cc[mi].x) * FATOM;
            fb[mi] = symb + (size_t)(bb + cc[mi].y) * FATOM;
            pf[mi] = pairfb + (size_t)pv[mi] * FPAIR;
        }

        // ---- Layer 1: pipelined A-gather + reg-resident weights ----
        f32x4 acc[4][2];
#pragma unroll
        for (int mi = 0; mi < 4; ++mi)
#pragma unroll
            for (int j = 0; j < 2; ++j)
                acc[mi][j] = (f32x4){b1v[j], b1v[j], b1v[j], b1v[j]};

        short8 aA[12], aB[12];
        LOADA(aA, 0);
        LOADA(aB, 1);
        L1MFMA(0, aA);
        LOADA(aA, 2);
        L1MFMA(1, aB);
        LOADA(aB, 3);
        L1MFMA(2, aA);
        L1MFMA(3, aB);

        // celu + swizzled H1 store
#pragma unroll
        for (int mi = 0; mi < 4; ++mi)
#pragma unroll
            for (int j = 0; j < 2; ++j)
#pragma unroll
                for (int r2 = 0; r2 < 4; ++r2) {
                    int m = mi * 16 + 4 * lg + r2;
                    int n = 32 * w + 16 * j + lr;
                    float h = celu1(acc[mi][j][r2]);
                    H1s[buf][m * HH1 + ((((n >> 3) ^ (m & 7))) << 3) + (n & 7)] = f2bf(h);
                }
        __syncthreads();

        // ---- Layer 2: W2 in regs, H1 fragments from LDS ----
        int m2 = 16 * w + lr;
        int mx = m2 & 7;
        const short* h1base = &H1s[buf][m2 * HH1];
        short8 bh0 = *(const short8*)(h1base + (((0 * 4 + lg) ^ mx) << 3));
        short8 bh1 = *(const short8*)(h1base + (((1 * 4 + lg) ^ mx) << 3));
        short8 bh2 = *(const short8*)(h1base + (((2 * 4 + lg) ^ mx) << 3));
        short8 bh3 = *(const short8*)(h1base + (((3 * 4 + lg) ^ mx) << 3));

        float s0 = 0.f, s1 = 0.f;
#pragma unroll
        for (int t6 = 0; t6 < 6; ++t6) {
            f32x4 a2;
#pragma unroll
            for (int r2 = 0; r2 < 4; ++r2) a2[r2] = b2v[t6][r2];
            a2 = __builtin_amdgcn_mfma_f32_16x16x32_bf16(w2r[t6][0], bh0, a2, 0, 0, 0);
            a2 = __builtin_amdgcn_mfma_f32_16x16x32_bf16(w2r[t6][1], bh1, a2, 0, 0, 0);
            a2 = __builtin_amdgcn_mfma_f32_16x16x32_bf16(w2r[t6][2], bh2, a2, 0, 0, 0);
            a2 = __builtin_amdgcn_mfma_f32_16x16x32_bf16(w2r[t6][3], bh3, a2, 0, 0, 0);
            // ---- Layer 3 partial: in-register ----
#pragma unroll
            for (int r2 = 0; r2 < 4; ++r2) {
                float h = celu1(a2[r2]);
                s0 = fmaf(h, w3v[t6][r2].x, s0);
                s1 = fmaf(h, w3v[t6][r2].y, s1);
            }
        }
        // reduce over lg (lane bits 4,5)
        s0 += __shfl_xor(s0, 16); s0 += __shfl_xor(s0, 32);
        s1 += __shfl_xor(s1, 16); s1 += __shfl_xor(s1, 32);
        if (lg == 0) {
            int ii = tb + m2;
            if (ii < cnt) {
                int p = bucket_e[ii];
                float2 o2; o2.x = s0 + b3v.x; o2.y = s1 + b3v.y;
                *(float2*)(out + 2 * (size_t)p) = o2;
            }
        }
    }
}

extern "C" void kernel_launch(void* const* d_in, const int* in_sizes, int n_in,
                              void* d_out, int out_size, void* d_ws, size_t ws_size,
                              hipStream_t stream)
{
    const int*   elements = (const int*)d_in[0];
    const int*   conn     = (const int*)d_in[1];
    const float* sym      = (const float*)d_in[2];
    const float* pairf    = (const float*)d_in[3];
    const float* W1       = (const float*)d_in[4];
    const float* b1       = (const float*)d_in[5];
    const float* W2       = (const float*)d_in[6];
    const float* b2       = (const float*)d_in[7];
    const float* W3       = (const float*)d_in[8];
    const float* b3       = (const float*)d_in[9];
    float* out = (float*)d_out;

    int* wsi    = (int*)d_ws;
    int* counts = wsi + WS_COUNTS;
    int* bucket = wsi + WS_BUCKET;

    short* bfb    = (short*)(wsi + WS_BF);
    short* symb   = bfb;
    short* pairfb = bfb + SYM_N;
    short* w1tb   = bfb + SYM_N + PAIR_N;
    short* w2tb   = bfb + SYM_N + PAIR_N + W1T_N;

    hipMemsetAsync((void*)counts, 0, NEXP * sizeof(int), stream);

    k_prep<<<PREP_GRID, 256, 0, stream>>>(sym, pairf, symb, pairfb,
                                          W1, W2, w1tb, w2tb,
                                          conn, elements, counts, bucket, out);
    k_moe<<<256, 256, 0, stream>>>(counts, bucket, conn, symb, pairfb,
                                   w1tb, w2tb, b1, b2, W3, b3, out);
}

// Round 7
// 35.735 us; speedup vs baseline: 1.9668x; 1.9668x over previous
//
#include <hip/hip_runtime.h>
#include <math.h>

typedef __attribute__((ext_vector_type(8))) short short8;
typedef __attribute__((ext_vector_type(4))) float f32x4;

namespace {
constexpr int NEL   = 4;
constexpr int NEXP  = 16;
constexpr int Bb    = 128;
constexpr int Aa    = 128;
constexpr int Cc    = 256;
constexpr int FATOM = 176;
constexpr int FPAIR = 32;
constexpr int FIN   = 384;
constexpr int HH1   = 128;
constexpr int HH2   = 96;
constexpr int NP    = Bb * Cc;               // 32768
constexpr int BUCKET_CAP = 4096;

// ws int offsets
constexpr int WS_COUNTS = 0;                 // 16 ints
constexpr int WS_BUCKET = 64;                // 16 * 4096 ints
constexpr int WS_BF     = 65600;             // shorts from here (16B aligned)
constexpr int SYM_N   = Bb * Aa * FATOM;     // 2,883,584
constexpr int PAIR_N  = Bb * Cc * FPAIR;     // 1,048,576

// packed per-expert weights: W1 [12][128][32] then W2 [4][96][32]
constexpr int W2_OFF = 12 * HH1 * 32;        // 49152 shorts
constexpr int WPK_E  = W2_OFF + 4 * HH2 * 32; // 61440 shorts (120 KB)

// fused prep grid layout
constexpr int CVT_BLOCKS = (SYM_N / 4 + PAIR_N / 4) / 256;  // 3840
constexpr int W1_BLOCKS  = 768;
constexpr int W2_BLOCKS  = 192;
constexpr int IDX_BLOCKS = NP / 256;                        // 128
constexpr int W1_BASE  = CVT_BLOCKS;
constexpr int W2_BASE  = W1_BASE + W1_BLOCKS;
constexpr int IDX_BASE = W2_BASE + W2_BLOCKS;
constexpr int PREP_GRID = IDX_BASE + IDX_BLOCKS;            // 4928
}

__device__ inline float bf2f(short s) {
    unsigned u = ((unsigned)(unsigned short)s) << 16;
    return __builtin_bit_cast(float, u);
}
__device__ inline short f2bf(float f) {
    unsigned u = __builtin_bit_cast(unsigned, f);
    unsigned r = (u + 0x7FFFu + ((u >> 16) & 1u)) >> 16;
    return (short)r;
}
__device__ inline float celu1(float v) {
    return v > 0.f ? v : (__expf(v) - 1.0f);
}

// ---- fused prep: cvt_x | W1 pack | W2 pack | expert index ----
__global__ __launch_bounds__(256) void k_prep(
    const float* __restrict__ sym, const float* __restrict__ pairf,
    short* __restrict__ symb, short* __restrict__ pairfb,
    const float* __restrict__ W1, const float* __restrict__ W2,
    short* __restrict__ wpk,
    const int* __restrict__ conn, const int* __restrict__ elements,
    int* __restrict__ counts, int* __restrict__ bucket,
    float* __restrict__ out)
{
    __shared__ float T[32][33];
    __shared__ int sh_cnt[NEXP], sh_base[NEXP];

    int bid = blockIdx.x;
    int t = threadIdx.x;

    if (bid < CVT_BLOCKS) {
        int i = bid * 256 + t;
        constexpr int NS4 = SYM_N / 4;
        const float4* src; short* dst; int j;
        if (i < NS4) { src = (const float4*)sym;   dst = symb;   j = i; }
        else         { src = (const float4*)pairf; dst = pairfb; j = i - NS4; }
        float4 v = src[j];
        short4 o;
        o.x = f2bf(v.x); o.y = f2bf(v.y); o.z = f2bf(v.z); o.w = f2bf(v.w);
        *(short4*)(dst + 4 * (size_t)j) = o;
    } else if (bid < IDX_BASE) {
        const float* src; short* dst; int K, N, k0, n0;
        if (bid < W2_BASE) {
            int b1i = bid - W1_BASE;
            int e = b1i / 48, tl = b1i % 48;
            K = FIN; N = HH1; k0 = (tl % 12) * 32; n0 = (tl / 12) * 32;
            src = W1 + (size_t)e * K * N;
            dst = wpk + (size_t)e * WPK_E;
        } else {
            int b2i = bid - W2_BASE;
            int e = b2i / 12, tl = b2i % 12;
            K = HH1; N = HH2; k0 = (tl % 4) * 32; n0 = (tl / 4) * 32;
            src = W2 + (size_t)e * K * N;
            dst = wpk + (size_t)e * WPK_E + W2_OFF;
        }
        int tx = t & 31, ty = t >> 5;
        int ks = k0 >> 5;
#pragma unroll
        for (int j = 0; j < 4; ++j) {
            int r = ty + 8 * j;
            T[r][tx] = src[(size_t)(k0 + r) * N + n0 + tx];
        }
        __syncthreads();
#pragma unroll
        for (int j = 0; j < 4; ++j) {
            int n = n0 + ty + 8 * j;
            dst[(size_t)(ks * N + n) * 32 + tx] = f2bf(T[tx][ty + 8 * j]);
        }
    } else {
        int p = (bid - IDX_BASE) * 256 + t;
        if (t < NEXP) sh_cnt[t] = 0;
        __syncthreads();
        int e = -1, r = 0;
        {
            int c0 = conn[2 * p], c1 = conn[2 * p + 1];
            if (c0 != -1) {
                int b = p / Cc;
                int i0 = b * Aa + c0; if (i0 < 0) i0 += Bb * Aa;
                int i1 = b * Aa + c1; if (i1 < 0) i1 += Bb * Aa;
                e = elements[i0] * NEL + elements[i1];
            }
            if (e < 0 || e >= NEXP) {
                out[2 * p] = 0.f; out[2 * p + 1] = 0.f;
                e = -1;
            } else {
                r = atomicAdd(&sh_cnt[e], 1);
            }
        }
        __syncthreads();
        if (t < NEXP) sh_base[t] = (sh_cnt[t] > 0) ? atomicAdd(&counts[t], sh_cnt[t]) : 0;
        __syncthreads();
        if (e >= 0) {
            int pos = sh_base[e] + r;
            if (pos < BUCKET_CAP) bucket[e * BUCKET_CAP + pos] = p;
        }
    }
}

// ---- MFMA MoE: expert-persistent blocks, weights in LDS ----
// grid = 256 blocks; e = bid & 15 (all 16 blocks of an expert on XCD e&7).
// 512 threads = 8 waves = 2 waves/SIMD (LDS 152KB -> 1 block/CU).
// Each wave owns independent 16-pair tiles; H1 is wave-private LDS.
__global__ __launch_bounds__(512, 2) void k_moe(
    const int* __restrict__ counts, const int* __restrict__ bucket,
    const int* __restrict__ conn,
    const short* __restrict__ symb, const short* __restrict__ pairfb,
    const short* __restrict__ wpk,
    const float* __restrict__ b1, const float* __restrict__ b2,
    const float* __restrict__ W3, const float* __restrict__ b3,
    float* __restrict__ out)
{
    __shared__ short Wlds[WPK_E];              // 120 KB: W1 [12][128][32] | W2 [4][96][32]
    __shared__ short H1s[8][16 * HH1];         // 8 x 4 KB, per-wave private, XOR-swizzled

    int e     = blockIdx.x & 15;
    int shard = blockIdx.x >> 4;
    int cnt = counts[e];
    if (cnt > BUCKET_CAP) cnt = BUCKET_CAP;

    int t = threadIdx.x;
    int w = t >> 6;
    int lane = t & 63;
    int lr = lane & 15, lg = (lane >> 4) & 3;

    // ---- stage expert weights into LDS (reg-staged, linear layout) ----
    const short* wsrc = wpk + (size_t)e * WPK_E;
    {
        short8 v[15];
#pragma unroll
        for (int r = 0; r < 15; ++r) v[r] = *(const short8*)(wsrc + r * 4096 + t * 8);
#pragma unroll
        for (int r = 0; r < 15; ++r) *(short8*)&Wlds[r * 4096 + t * 8] = v[r];
    }

    // per-wave constants (tile-invariant)
    float b1v[8];
#pragma unroll
    for (int j = 0; j < 8; ++j) b1v[j] = b1[e * HH1 + j * 16 + lr];
    float2 b3v = ((const float2*)b3)[e];

    __syncthreads();

    int nt = (cnt + 15) >> 4;
    const int* bucket_e = bucket + e * BUCKET_CAP;
    short* h1w = &H1s[w][0];

    for (int tile = shard * 8 + w; tile < nt; tile += 128) {
        int ii = tile * 16 + lr;
        int p = bucket_e[ii < cnt ? ii : cnt - 1];
        int2 c = ((const int2*)conn)[p];
        int bb = (p >> 8) << 7;                    // batch * Aa
        const short* fa = symb + (size_t)(bb + c.x) * FATOM;
        const short* fb = symb + (size_t)(bb + c.y) * FATOM;
        const short* pf = pairfb + (size_t)p * FPAIR;

        // ---- A-gather: all 12 K-step fragments issued up-front ----
        short8 a[12];
        a[0]  = *(const short8*)(fa + 8 * lg);
        a[1]  = *(const short8*)(fa + 32 + 8 * lg);
        a[2]  = *(const short8*)(fa + 64 + 8 * lg);
        a[3]  = *(const short8*)(fa + 96 + 8 * lg);
        a[4]  = *(const short8*)(fa + 128 + 8 * lg);
        a[5]  = *(const short8*)((lg < 2 ? fa + 160 : fb - 16) + 8 * lg);
        a[6]  = *(const short8*)(fb + 16 + 8 * lg);
        a[7]  = *(const short8*)(fb + 48 + 8 * lg);
        a[8]  = *(const short8*)(fb + 80 + 8 * lg);
        a[9]  = *(const short8*)(fb + 112 + 8 * lg);
        a[10] = *(const short8*)(fb + 144 + 8 * lg);
        a[11] = *(const short8*)(pf + 8 * lg);

        // ---- Layer 1: 16 pairs x 128 cols, W1 frags from LDS ----
        f32x4 acc[8];
#pragma unroll
        for (int j = 0; j < 8; ++j) acc[j] = (f32x4){b1v[j], b1v[j], b1v[j], b1v[j]};
#pragma unroll
        for (int ks = 0; ks < 12; ++ks) {
#pragma unroll
            for (int j = 0; j < 8; ++j) {
                short8 bw = *(const short8*)&Wlds[(ks * HH1 + j * 16 + lr) * 32 + 8 * lg];
                acc[j] = __builtin_amdgcn_mfma_f32_16x16x32_bf16(a[ks], bw, acc[j], 0, 0, 0);
            }
        }

        // ---- celu + swizzled H1 store (wave-private; no barrier) ----
#pragma unroll
        for (int j = 0; j < 8; ++j)
#pragma unroll
            for (int r2 = 0; r2 < 4; ++r2) {
                int m = 4 * lg + r2;
                int n = 16 * j + lr;
                h1w[m * HH1 + (((n >> 3) ^ (m & 7)) << 3) + (n & 7)] = f2bf(celu1(acc[j][r2]));
            }
        asm volatile("s_waitcnt lgkmcnt(0)" ::: "memory");
        __builtin_amdgcn_sched_barrier(0);

        // ---- Layer 2 (swapped) + Layer 3 in-register ----
        int mx = lr & 7;
        short8 bh[4];
#pragma unroll
        for (int q = 0; q < 4; ++q)
            bh[q] = *(const short8*)&h1w[lr * HH1 + (((q * 4 + lg) ^ mx) << 3)];

        float s0 = 0.f, s1 = 0.f;
#pragma unroll
        for (int t6 = 0; t6 < 6; ++t6) {
            int n2b = 16 * t6 + 4 * lg;
            float4 bb4 = *(const float4*)&b2[e * HH2 + n2b];
            f32x4 a2;
            a2[0] = bb4.x; a2[1] = bb4.y; a2[2] = bb4.z; a2[3] = bb4.w;
#pragma unroll
            for (int q = 0; q < 4; ++q) {
                short8 aw = *(const short8*)&Wlds[W2_OFF + (q * HH2 + 16 * t6 + lr) * 32 + 8 * lg];
                a2 = __builtin_amdgcn_mfma_f32_16x16x32_bf16(aw, bh[q], a2, 0, 0, 0);
            }
            float4 w3a = *(const float4*)&W3[(size_t)(e * HH2 + n2b) * 2];
            float4 w3b = *(const float4*)&W3[(size_t)(e * HH2 + n2b) * 2 + 4];
            float h0 = celu1(a2[0]), h1 = celu1(a2[1]), h2 = celu1(a2[2]), h3 = celu1(a2[3]);
            s0 = fmaf(h0, w3a.x, fmaf(h1, w3a.z, fmaf(h2, w3b.x, fmaf(h3, w3b.z, s0))));
            s1 = fmaf(h0, w3a.y, fmaf(h1, w3a.w, fmaf(h2, w3b.y, fmaf(h3, w3b.w, s1))));
        }
        s0 += __shfl_xor(s0, 16); s0 += __shfl_xor(s0, 32);
        s1 += __shfl_xor(s1, 16); s1 += __shfl_xor(s1, 32);
        if (((lane >> 4) & 3) == 0 && ii < cnt) {
            float2 o2; o2.x = s0 + b3v.x; o2.y = s1 + b3v.y;
            *(float2*)(out + 2 * (size_t)bucket_e[ii]) = o2;
        }
    }
}

extern "C" void kernel_launch(void* const* d_in, const int* in_sizes, int n_in,
                              void* d_out, int out_size, void* d_ws, size_t ws_size,
                              hipStream_t stream)
{
    const int*   elements = (const int*)d_in[0];
    const int*   conn     = (const int*)d_in[1];
    const float* sym      = (const float*)d_in[2];
    const float* pairf    = (const float*)d_in[3];
    const float* W1       = (const float*)d_in[4];
    const float* b1       = (const float*)d_in[5];
    const float* W2       = (const float*)d_in[6];
    const float* b2       = (const float*)d_in[7];
    const float* W3       = (const float*)d_in[8];
    const float* b3       = (const float*)d_in[9];
    float* out = (float*)d_out;

    int* wsi    = (int*)d_ws;
    int* counts = wsi + WS_COUNTS;
    int* bucket = wsi + WS_BUCKET;

    short* bfb    = (short*)(wsi + WS_BF);
    short* symb   = bfb;
    short* pairfb = bfb + SYM_N;
    short* wpk    = bfb + SYM_N + PAIR_N;     // NEXP * WPK_E shorts

    hipMemsetAsync((void*)counts, 0, NEXP * sizeof(int), stream);

    k_prep<<<PREP_GRID, 256, 0, stream>>>(sym, pairf, symb, pairfb,
                                          W1, W2, wpk,
                                          conn, elements, counts, bucket, out);
    k_moe<<<256, 512, 0, stream>>>(counts, bucket, conn, symb, pairfb, wpk,
                                   b1, b2, W3, b3, out);
}